// Round 1
// baseline (693.548 us; speedup 1.0000x reference)
//
#include <hip/hip_runtime.h>
#include <hip/hip_bf16.h>
#include <math.h>

#define NN 50000
#define EE 800000
#define IN_C 128
#define HID 64
#define HEADS 4

// ---------------- CSR build ----------------

__global__ void degree_kernel(const int* __restrict__ ei, int* __restrict__ deg) {
    int i = blockIdx.x * blockDim.x + threadIdx.x;
    if (i < EE) atomicAdd(&deg[ei[EE + i]], 1);
}

// single block, 256 threads: exclusive scan of deg[0..N) -> row_ptr[0..N], copy to cursor
__global__ void scan_kernel(const int* __restrict__ deg, int* __restrict__ row_ptr,
                            int* __restrict__ cursor) {
    __shared__ int part[256];
    int tid = threadIdx.x;
    const int chunk = (NN + 255) / 256;
    int base = tid * chunk;
    int s = 0;
    for (int j = 0; j < chunk; j++) {
        int idx = base + j;
        if (idx < NN) s += deg[idx];
    }
    part[tid] = s;
    __syncthreads();
    if (tid == 0) {
        int run = 0;
        for (int i = 0; i < 256; i++) { int t = part[i]; part[i] = run; run += t; }
        row_ptr[NN] = run;   // == EE
    }
    __syncthreads();
    int run = part[tid];
    for (int j = 0; j < chunk; j++) {
        int idx = base + j;
        if (idx < NN) {
            row_ptr[idx] = run;
            cursor[idx] = run;
            run += deg[idx];
        }
    }
}

__global__ void scatter_kernel(const int* __restrict__ ei, int* __restrict__ cursor,
                               int* __restrict__ csr_src) {
    int i = blockIdx.x * blockDim.x + threadIdx.x;
    if (i < EE) {
        int d = ei[EE + i];
        int pos = atomicAdd(&cursor[d], 1);
        csr_src[pos] = ei[i];
    }
}

// ---------------- fp32 tiled GEMM: C[M,N] = A[M,K] @ B[K,N] ----------------
// BM=BN=64, BK=16, 256 threads, 4x4 micro-tile. N,K assumed divisible (256/64, 128/256).
__global__ void gemm_kernel(const float* __restrict__ A, const float* __restrict__ B,
                            float* __restrict__ C, int M, int N, int K) {
    __shared__ float As[16][65];
    __shared__ float Bs[16][65];
    int tid = threadIdx.x;
    int tx = tid & 15, ty = tid >> 4;
    int bm = blockIdx.y * 64;
    int bn = blockIdx.x * 64;
    float acc[4][4] = {};
    for (int k0 = 0; k0 < K; k0 += 16) {
        #pragma unroll
        for (int i = 0; i < 4; i++) {
            int idx = tid + i * 256;
            int r = idx >> 4, c = idx & 15;
            int row = bm + r;
            As[c][r] = (row < M) ? A[(size_t)row * K + k0 + c] : 0.f;
        }
        #pragma unroll
        for (int i = 0; i < 4; i++) {
            int idx = tid + i * 256;
            int r = idx >> 6, c = idx & 63;
            Bs[r][c] = B[(size_t)(k0 + r) * N + bn + c];
        }
        __syncthreads();
        #pragma unroll
        for (int k = 0; k < 16; k++) {
            float a[4], b[4];
            #pragma unroll
            for (int i = 0; i < 4; i++) a[i] = As[k][ty * 4 + i];
            #pragma unroll
            for (int j = 0; j < 4; j++) b[j] = Bs[k][tx * 4 + j];
            #pragma unroll
            for (int i = 0; i < 4; i++)
                #pragma unroll
                for (int j = 0; j < 4; j++)
                    acc[i][j] += a[i] * b[j];
        }
        __syncthreads();
    }
    #pragma unroll
    for (int i = 0; i < 4; i++) {
        int row = bm + ty * 4 + i;
        if (row < M) {
            #pragma unroll
            for (int j = 0; j < 4; j++)
                C[(size_t)row * N + bn + tx * 4 + j] = acc[i][j];
        }
    }
}

// ---------------- attention logits ----------------
// layer 1: one block (256 thr) per node; wave w reduces head w over 64 channels
__global__ void alpha1_kernel(const float* __restrict__ h1, const float* __restrict__ a_src,
                              const float* __restrict__ a_dst, float* __restrict__ as_out,
                              float* __restrict__ ad_out) {
    int n = blockIdx.x;
    int tid = threadIdx.x;
    int head = tid >> 6, lane = tid & 63;
    float v = h1[(size_t)n * 256 + tid];
    float ps = v * a_src[tid];
    float pd = v * a_dst[tid];
    #pragma unroll
    for (int off = 32; off; off >>= 1) {
        ps += __shfl_down(ps, off);
        pd += __shfl_down(pd, off);
    }
    if (lane == 0) {
        as_out[n * 4 + head] = ps;
        ad_out[n * 4 + head] = pd;
    }
}

// layer 2: 4 nodes per 256-thread block, wave per node, 64 channels, 1 head
__global__ void alpha2_kernel(const float* __restrict__ g, const float* __restrict__ a_src,
                              const float* __restrict__ a_dst, float* __restrict__ as_out,
                              float* __restrict__ ad_out) {
    int tid = threadIdx.x;
    int wv = tid >> 6, lane = tid & 63;
    int n = blockIdx.x * 4 + wv;
    if (n >= NN) return;
    float v = g[(size_t)n * 64 + lane];
    float ps = v * a_src[lane];
    float pd = v * a_dst[lane];
    #pragma unroll
    for (int off = 32; off; off >>= 1) {
        ps += __shfl_down(ps, off);
        pd += __shfl_down(pd, off);
    }
    if (lane == 0) {
        as_out[n] = ps;
        ad_out[n] = pd;
    }
}

// ---------------- layer-1 aggregation (block = node, 256 channels) ----------------
// out h2[n,c] = elu( sum_e softmax_w(e) * h1[src_e, c] + b1[c] )
__global__ void agg1_kernel(const float* __restrict__ h1, const int* __restrict__ row_ptr,
                            const int* __restrict__ csr_src, const float* __restrict__ as,
                            const float* __restrict__ ad, const float* __restrict__ b1,
                            float* __restrict__ h2) {
    int n = blockIdx.x;
    int tid = threadIdx.x;
    int head = tid >> 6;
    int lane = tid & 63;
    int start = row_ptr[n], end = row_ptr[n + 1];
    __shared__ float sden[4];
    __shared__ float sinv[4];
    __shared__ int ssrc[64];
    __shared__ float wch[64 * 4];
    float ad0 = ad[n * 4 + 0], ad1 = ad[n * 4 + 1];
    float ad2 = ad[n * 4 + 2], ad3 = ad[n * 4 + 3];
    if (tid < 4) sden[tid] = 0.f;
    __syncthreads();
    // phase 1: denominator per head
    float l0 = 0.f, l1 = 0.f, l2 = 0.f, l3 = 0.f;
    for (int i = start + tid; i < end; i += 256) {
        int s = csr_src[i];
        float e;
        e = as[s * 4 + 0] + ad0; e = e > 0.f ? e : 0.2f * e; l0 += __expf(e);
        e = as[s * 4 + 1] + ad1; e = e > 0.f ? e : 0.2f * e; l1 += __expf(e);
        e = as[s * 4 + 2] + ad2; e = e > 0.f ? e : 0.2f * e; l2 += __expf(e);
        e = as[s * 4 + 3] + ad3; e = e > 0.f ? e : 0.2f * e; l3 += __expf(e);
    }
    #pragma unroll
    for (int off = 32; off; off >>= 1) {
        l0 += __shfl_down(l0, off); l1 += __shfl_down(l1, off);
        l2 += __shfl_down(l2, off); l3 += __shfl_down(l3, off);
    }
    if (lane == 0) {
        atomicAdd(&sden[0], l0); atomicAdd(&sden[1], l1);
        atomicAdd(&sden[2], l2); atomicAdd(&sden[3], l3);
    }
    __syncthreads();
    if (tid < 4) sinv[tid] = 1.f / (sden[tid] + 1e-16f);
    __syncthreads();
    // phase 2: weighted aggregation, 64-edge chunks staged in LDS
    float acc = 0.f;
    for (int c0 = start; c0 < end; c0 += 64) {
        int m = min(64, end - c0);
        if (tid < m) {
            int s = csr_src[c0 + tid];
            ssrc[tid] = s;
            float e0 = as[s * 4 + 0] + ad0; e0 = e0 > 0.f ? e0 : 0.2f * e0;
            float e1 = as[s * 4 + 1] + ad1; e1 = e1 > 0.f ? e1 : 0.2f * e1;
            float e2 = as[s * 4 + 2] + ad2; e2 = e2 > 0.f ? e2 : 0.2f * e2;
            float e3 = as[s * 4 + 3] + ad3; e3 = e3 > 0.f ? e3 : 0.2f * e3;
            wch[tid * 4 + 0] = __expf(e0) * sinv[0];
            wch[tid * 4 + 1] = __expf(e1) * sinv[1];
            wch[tid * 4 + 2] = __expf(e2) * sinv[2];
            wch[tid * 4 + 3] = __expf(e3) * sinv[3];
        }
        __syncthreads();
        for (int j = 0; j < m; j++) {
            acc += h1[(size_t)ssrc[j] * 256 + tid] * wch[j * 4 + head];
        }
        __syncthreads();
    }
    float r = acc + b1[tid];
    h2[(size_t)n * 256 + tid] = r > 0.f ? r : expm1f(r);
}

// ---------------- layer-2 aggregation (wave = node, 64 channels, 1 head) ----------------
__global__ void agg2_kernel(const float* __restrict__ g, const int* __restrict__ row_ptr,
                            const int* __restrict__ csr_src, const float* __restrict__ as,
                            const float* __restrict__ ad, const float* __restrict__ b2,
                            float* __restrict__ out) {
    int tid = threadIdx.x;
    int wv = tid >> 6, lane = tid & 63;
    int n = blockIdx.x * 4 + wv;
    if (n >= NN) return;
    int start = row_ptr[n], end = row_ptr[n + 1];
    float adv = ad[n];
    float l = 0.f;
    for (int i = start + lane; i < end; i += 64) {
        float e = as[csr_src[i]] + adv;
        e = e > 0.f ? e : 0.2f * e;
        l += __expf(e);
    }
    #pragma unroll
    for (int off = 32; off; off >>= 1) l += __shfl_down(l, off);
    l = __shfl(l, 0);
    float inv = 1.f / (l + 1e-16f);
    float acc = 0.f;
    for (int i = start; i < end; i++) {
        int s = csr_src[i];
        float e = as[s] + adv;
        e = e > 0.f ? e : 0.2f * e;
        acc += g[(size_t)s * 64 + lane] * (__expf(e) * inv);
    }
    float r = acc + b2[lane];
    out[(size_t)n * 64 + lane] = r > 0.f ? r : expm1f(r);
}

// ---------------- launch ----------------

extern "C" void kernel_launch(void* const* d_in, const int* in_sizes, int n_in,
                              void* d_out, int out_size, void* d_ws, size_t ws_size,
                              hipStream_t stream) {
    const float* x      = (const float*)d_in[0];
    const int*   ei     = (const int*)d_in[1];
    const float* W1     = (const float*)d_in[2];
    const float* a_src1 = (const float*)d_in[3];
    const float* a_dst1 = (const float*)d_in[4];
    const float* b1     = (const float*)d_in[5];
    const float* W2     = (const float*)d_in[6];
    const float* a_src2 = (const float*)d_in[7];
    const float* a_dst2 = (const float*)d_in[8];
    const float* b2     = (const float*)d_in[9];
    float* out = (float*)d_out;

    char* base = (char*)d_ws;
    size_t off = 0;
    auto alloc = [&](size_t bytes) -> void* {
        void* p = base + off;
        off = (off + bytes + 255) & ~(size_t)255;
        return p;
    };
    int*   deg     = (int*)alloc(NN * sizeof(int));
    int*   row_ptr = (int*)alloc((NN + 1) * sizeof(int));
    int*   cursor  = (int*)alloc(NN * sizeof(int));
    int*   csr_src = (int*)alloc(EE * sizeof(int));
    float* h1      = (float*)alloc((size_t)NN * 256 * sizeof(float));
    float* as1     = (float*)alloc((size_t)NN * 4 * sizeof(float));
    float* ad1     = (float*)alloc((size_t)NN * 4 * sizeof(float));
    float* h2      = (float*)alloc((size_t)NN * 256 * sizeof(float));
    float* g2      = (float*)alloc((size_t)NN * 64 * sizeof(float));
    float* as2     = (float*)alloc((size_t)NN * sizeof(float));
    float* ad2     = (float*)alloc((size_t)NN * sizeof(float));

    hipMemsetAsync(deg, 0, NN * sizeof(int), stream);

    int eblocks = (EE + 255) / 256;
    degree_kernel<<<eblocks, 256, 0, stream>>>(ei, deg);
    scan_kernel<<<1, 256, 0, stream>>>(deg, row_ptr, cursor);
    scatter_kernel<<<eblocks, 256, 0, stream>>>(ei, cursor, csr_src);

    // layer 1
    dim3 g1((HEADS * HID) / 64, (NN + 63) / 64);
    gemm_kernel<<<g1, 256, 0, stream>>>(x, W1, h1, NN, HEADS * HID, IN_C);
    alpha1_kernel<<<NN, 256, 0, stream>>>(h1, a_src1, a_dst1, as1, ad1);
    agg1_kernel<<<NN, 256, 0, stream>>>(h1, row_ptr, csr_src, as1, ad1, b1, h2);

    // layer 2
    dim3 gg(HID / 64, (NN + 63) / 64);
    gemm_kernel<<<gg, 256, 0, stream>>>(h2, W2, g2, NN, HID, HEADS * HID);
    alpha2_kernel<<<(NN + 3) / 4, 256, 0, stream>>>(g2, a_src2, a_dst2, as2, ad2);
    agg2_kernel<<<NN / 4, 256, 0, stream>>>(g2, row_ptr, csr_src, as2, ad2, b2, out);
}

// Round 2
// 640.923 us; speedup vs baseline: 1.0821x; 1.0821x over previous
//
#include <hip/hip_runtime.h>
#include <hip/hip_bf16.h>
#include <math.h>

#define NN 50000
#define EE 800000
#define IN_C 128
#define HID 64
#define HEADS 4

// ---------------- CSR build ----------------

__global__ void degree_kernel(const int* __restrict__ ei, int* __restrict__ deg) {
    int i = blockIdx.x * blockDim.x + threadIdx.x;
    if (i < EE) atomicAdd(&deg[ei[EE + i]], 1);
}

// single block, 1024 threads: exclusive scan of deg -> row_ptr, cursor
__global__ void scan_kernel(const int* __restrict__ deg, int* __restrict__ row_ptr,
                            int* __restrict__ cursor) {
    __shared__ int wsum[16];
    int tid = threadIdx.x;
    const int chunk = (NN + 1023) / 1024;
    int base = tid * chunk;
    int s = 0;
    for (int j = 0; j < chunk; j++) {
        int idx = base + j;
        if (idx < NN) s += deg[idx];
    }
    int incl = s;
    #pragma unroll
    for (int off = 1; off < 64; off <<= 1) {
        int t = __shfl_up(incl, off);
        if ((tid & 63) >= off) incl += t;
    }
    if ((tid & 63) == 63) wsum[tid >> 6] = incl;
    __syncthreads();
    if (tid == 0) {
        int run = 0;
        #pragma unroll
        for (int i = 0; i < 16; i++) { int t = wsum[i]; wsum[i] = run; run += t; }
        row_ptr[NN] = run;   // == EE
    }
    __syncthreads();
    int excl = incl - s + wsum[tid >> 6];
    for (int j = 0; j < chunk; j++) {
        int idx = base + j;
        if (idx < NN) {
            row_ptr[idx] = excl;
            cursor[idx] = excl;
            excl += deg[idx];
        }
    }
}

__global__ void scatter_kernel(const int* __restrict__ ei, int* __restrict__ cursor,
                               int* __restrict__ csr_src) {
    int i = blockIdx.x * blockDim.x + threadIdx.x;
    if (i < EE) {
        int d = ei[EE + i];
        int pos = atomicAdd(&cursor[d], 1);
        csr_src[pos] = ei[i];
    }
}

// ---------------- fp32 tiled GEMM: C[M,N] = A[M,K] @ B[K,N] ----------------
// 256 threads, BK=16, micro-tile TM x TN with ds_read_b128 fragment loads.
// Requires N % BN == 0, K % 16 == 0.
template<int BM, int BN>
__global__ __launch_bounds__(256, 2) void gemm_t(const float* __restrict__ A,
                                                 const float* __restrict__ B,
                                                 float* __restrict__ C,
                                                 int M, int N, int K) {
    constexpr int BK = 16;
    constexpr int TM = BM / 16;
    constexpr int TN = BN / 16;
    __shared__ float As[BK][BM + 4];   // [k][m], stride (BM+4)*4 bytes % 16 == 0
    __shared__ float Bs[BK][BN + 4];   // [k][n]
    int tid = threadIdx.x;
    int tx = tid & 15, ty = tid >> 4;
    int bm = blockIdx.y * BM, bn = blockIdx.x * BN;
    float acc[TM][TN] = {};
    for (int k0 = 0; k0 < K; k0 += BK) {
        #pragma unroll
        for (int i = 0; i < BM * BK / 256; i++) {
            int idx = tid + i * 256;
            int c = idx & 15, r = idx >> 4;
            int row = bm + r;
            As[c][r] = (row < M) ? A[(size_t)row * K + k0 + c] : 0.f;
        }
        #pragma unroll
        for (int i = 0; i < BN * BK / 256; i++) {
            int idx = tid + i * 256;
            int r = idx / BN, c = idx % BN;
            Bs[r][c] = B[(size_t)(k0 + r) * N + bn + c];
        }
        __syncthreads();
        #pragma unroll
        for (int k = 0; k < BK; k++) {
            float a[TM], b[TN];
            #pragma unroll
            for (int i = 0; i < TM; i += 4)
                *(float4*)&a[i] = *(const float4*)&As[k][ty * TM + i];
            #pragma unroll
            for (int j = 0; j < TN; j += 4)
                *(float4*)&b[j] = *(const float4*)&Bs[k][tx * TN + j];
            #pragma unroll
            for (int i = 0; i < TM; i++)
                #pragma unroll
                for (int j = 0; j < TN; j++)
                    acc[i][j] += a[i] * b[j];
        }
        __syncthreads();
    }
    #pragma unroll
    for (int i = 0; i < TM; i++) {
        int row = bm + ty * TM + i;
        if (row < M) {
            #pragma unroll
            for (int j = 0; j < TN; j += 4) {
                float4 v = make_float4(acc[i][j], acc[i][j + 1], acc[i][j + 2], acc[i][j + 3]);
                *(float4*)&C[(size_t)row * N + bn + tx * TN + j] = v;
            }
        }
    }
}

// ---------------- attention logits ----------------
__global__ void alpha1_kernel(const float* __restrict__ h1, const float* __restrict__ a_src,
                              const float* __restrict__ a_dst, float* __restrict__ as_out,
                              float* __restrict__ ad_out) {
    int n = blockIdx.x;
    int tid = threadIdx.x;
    int head = tid >> 6, lane = tid & 63;
    float v = h1[(size_t)n * 256 + tid];
    float ps = v * a_src[tid];
    float pd = v * a_dst[tid];
    #pragma unroll
    for (int off = 32; off; off >>= 1) {
        ps += __shfl_down(ps, off);
        pd += __shfl_down(pd, off);
    }
    if (lane == 0) {
        as_out[n * 4 + head] = ps;
        ad_out[n * 4 + head] = pd;
    }
}

__global__ void alpha2_kernel(const float* __restrict__ g, const float* __restrict__ a_src,
                              const float* __restrict__ a_dst, float* __restrict__ as_out,
                              float* __restrict__ ad_out) {
    int tid = threadIdx.x;
    int wv = tid >> 6, lane = tid & 63;
    int n = blockIdx.x * 4 + wv;
    if (n >= NN) return;
    float v = g[(size_t)n * 64 + lane];
    float ps = v * a_src[lane];
    float pd = v * a_dst[lane];
    #pragma unroll
    for (int off = 32; off; off >>= 1) {
        ps += __shfl_down(ps, off);
        pd += __shfl_down(pd, off);
    }
    if (lane == 0) {
        as_out[n] = ps;
        ad_out[n] = pd;
    }
}

// ---------------- layer-1 aggregation: wave = node, lane = 4 channels ----------------
// h2[n,:] = elu( (1/den) * sum_e exp(leaky(e)) * h1[src_e,:] + b1 )
__global__ __launch_bounds__(256) void agg1_kernel(
        const float* __restrict__ h1, const int* __restrict__ row_ptr,
        const int* __restrict__ csr_src, const float* __restrict__ as,
        const float* __restrict__ ad, const float* __restrict__ b1,
        float* __restrict__ h2) {
    __shared__ int   ssrc[4][64];
    __shared__ float wch[4][64][4];
    int tid = threadIdx.x;
    int wv = tid >> 6, lane = tid & 63;
    int n = blockIdx.x * 4 + wv;
    if (n >= NN) return;
    int start = row_ptr[n], end = row_ptr[n + 1];
    float4 adv = ((const float4*)ad)[n];
    int whead = lane >> 4;
    float4 acc = make_float4(0.f, 0.f, 0.f, 0.f);
    float d0 = 0.f, d1 = 0.f, d2 = 0.f, d3 = 0.f;
    for (int c0 = start; c0 < end; c0 += 64) {
        int m = min(64, end - c0);
        if (lane < m) {
            int s = csr_src[c0 + lane];
            ssrc[wv][lane] = s;
            float4 asv = ((const float4*)as)[s];
            float e0 = asv.x + adv.x; e0 = e0 > 0.f ? e0 : 0.2f * e0; float x0 = __expf(e0);
            float e1 = asv.y + adv.y; e1 = e1 > 0.f ? e1 : 0.2f * e1; float x1 = __expf(e1);
            float e2 = asv.z + adv.z; e2 = e2 > 0.f ? e2 : 0.2f * e2; float x2 = __expf(e2);
            float e3 = asv.w + adv.w; e3 = e3 > 0.f ? e3 : 0.2f * e3; float x3 = __expf(e3);
            *(float4*)&wch[wv][lane][0] = make_float4(x0, x1, x2, x3);
            d0 += x0; d1 += x1; d2 += x2; d3 += x3;
        }
        for (int j = 0; j < m; j++) {
            int s = ssrc[wv][j];
            float w = wch[wv][j][whead];
            float4 hv = ((const float4*)h1)[(size_t)s * 64 + lane];
            acc.x += hv.x * w; acc.y += hv.y * w;
            acc.z += hv.z * w; acc.w += hv.w * w;
        }
    }
    #pragma unroll
    for (int off = 32; off; off >>= 1) {
        d0 += __shfl_down(d0, off); d1 += __shfl_down(d1, off);
        d2 += __shfl_down(d2, off); d3 += __shfl_down(d3, off);
    }
    d0 = __shfl(d0, 0); d1 = __shfl(d1, 0);
    d2 = __shfl(d2, 0); d3 = __shfl(d3, 0);
    float den = whead == 0 ? d0 : whead == 1 ? d1 : whead == 2 ? d2 : d3;
    float inv = 1.f / (den + 1e-16f);
    float4 bv = ((const float4*)b1)[lane];
    float4 r;
    r.x = acc.x * inv + bv.x; r.y = acc.y * inv + bv.y;
    r.z = acc.z * inv + bv.z; r.w = acc.w * inv + bv.w;
    r.x = r.x > 0.f ? r.x : expm1f(r.x);
    r.y = r.y > 0.f ? r.y : expm1f(r.y);
    r.z = r.z > 0.f ? r.z : expm1f(r.z);
    r.w = r.w > 0.f ? r.w : expm1f(r.w);
    ((float4*)h2)[(size_t)n * 64 + lane] = r;
}

// ---------------- layer-2 aggregation: wave = node, lane = channel ----------------
__global__ __launch_bounds__(256) void agg2_kernel(
        const float* __restrict__ g, const int* __restrict__ row_ptr,
        const int* __restrict__ csr_src, const float* __restrict__ as,
        const float* __restrict__ ad, const float* __restrict__ b2,
        float* __restrict__ out) {
    __shared__ int   ssrc[4][64];
    __shared__ float wts[4][64];
    int tid = threadIdx.x;
    int wv = tid >> 6, lane = tid & 63;
    int n = blockIdx.x * 4 + wv;
    if (n >= NN) return;
    int start = row_ptr[n], end = row_ptr[n + 1];
    float adv = ad[n];
    float acc = 0.f;
    float den = 0.f;
    for (int c0 = start; c0 < end; c0 += 64) {
        int m = min(64, end - c0);
        if (lane < m) {
            int s = csr_src[c0 + lane];
            ssrc[wv][lane] = s;
            float e = as[s] + adv;
            e = e > 0.f ? e : 0.2f * e;
            float x = __expf(e);
            wts[wv][lane] = x;
            den += x;
        }
        for (int j = 0; j < m; j++) {
            int s = ssrc[wv][j];
            float w = wts[wv][j];
            acc += g[(size_t)s * 64 + lane] * w;
        }
    }
    #pragma unroll
    for (int off = 32; off; off >>= 1) den += __shfl_down(den, off);
    den = __shfl(den, 0);
    float inv = 1.f / (den + 1e-16f);
    float r = acc * inv + b2[lane];
    out[(size_t)n * 64 + lane] = r > 0.f ? r : expm1f(r);
}

// ---------------- launch ----------------

extern "C" void kernel_launch(void* const* d_in, const int* in_sizes, int n_in,
                              void* d_out, int out_size, void* d_ws, size_t ws_size,
                              hipStream_t stream) {
    const float* x      = (const float*)d_in[0];
    const int*   ei     = (const int*)d_in[1];
    const float* W1     = (const float*)d_in[2];
    const float* a_src1 = (const float*)d_in[3];
    const float* a_dst1 = (const float*)d_in[4];
    const float* b1     = (const float*)d_in[5];
    const float* W2     = (const float*)d_in[6];
    const float* a_src2 = (const float*)d_in[7];
    const float* a_dst2 = (const float*)d_in[8];
    const float* b2     = (const float*)d_in[9];
    float* out = (float*)d_out;

    char* base = (char*)d_ws;
    size_t off = 0;
    auto alloc = [&](size_t bytes) -> void* {
        void* p = base + off;
        off = (off + bytes + 255) & ~(size_t)255;
        return p;
    };
    int*   deg     = (int*)alloc(NN * sizeof(int));
    int*   row_ptr = (int*)alloc((NN + 1) * sizeof(int));
    int*   cursor  = (int*)alloc(NN * sizeof(int));
    int*   csr_src = (int*)alloc(EE * sizeof(int));
    float* h1      = (float*)alloc((size_t)NN * 256 * sizeof(float));
    float* as1     = (float*)alloc((size_t)NN * 4 * sizeof(float));
    float* ad1     = (float*)alloc((size_t)NN * 4 * sizeof(float));
    float* h2      = (float*)alloc((size_t)NN * 256 * sizeof(float));
    float* g2      = (float*)alloc((size_t)NN * 64 * sizeof(float));
    float* as2     = (float*)alloc((size_t)NN * sizeof(float));
    float* ad2     = (float*)alloc((size_t)NN * sizeof(float));

    hipMemsetAsync(deg, 0, NN * sizeof(int), stream);

    int eblocks = (EE + 255) / 256;
    degree_kernel<<<eblocks, 256, 0, stream>>>(ei, deg);
    scan_kernel<<<1, 1024, 0, stream>>>(deg, row_ptr, cursor);
    scatter_kernel<<<eblocks, 256, 0, stream>>>(ei, cursor, csr_src);

    // layer 1: h1 = x @ W1   (50000x128 @ 128x256)
    {
        dim3 g((HEADS * HID) / 128, (NN + 127) / 128);
        gemm_t<128, 128><<<g, 256, 0, stream>>>(x, W1, h1, NN, HEADS * HID, IN_C);
    }
    alpha1_kernel<<<NN, 256, 0, stream>>>(h1, a_src1, a_dst1, as1, ad1);
    agg1_kernel<<<(NN + 3) / 4, 256, 0, stream>>>(h1, row_ptr, csr_src, as1, ad1, b1, h2);

    // layer 2: g2 = h2 @ W2  (50000x256 @ 256x64)
    {
        dim3 g(HID / 64, (NN + 127) / 128);
        gemm_t<128, 64><<<g, 256, 0, stream>>>(h2, W2, g2, NN, HID, HEADS * HID);
    }
    alpha2_kernel<<<(NN + 3) / 4, 256, 0, stream>>>(g2, a_src2, a_dst2, as2, ad2);
    agg2_kernel<<<(NN + 3) / 4, 256, 0, stream>>>(g2, row_ptr, csr_src, as2, ad2, b2, out);
}

// Round 3
// 466.963 us; speedup vs baseline: 1.4852x; 1.3725x over previous
//
#include <hip/hip_runtime.h>
#include <hip/hip_bf16.h>
#include <math.h>

#define NN 50000
#define EE 800000
#define IN_C 128
#define HID 64
#define HEADS 4
#define SCAN_BLOCKS ((NN + 255) / 256)   // 196

// ---------------- helpers ----------------

__device__ inline unsigned short f2bf(float f) {       // fp32 -> bf16 RNE
    unsigned u = __float_as_uint(f);
    unsigned r = (u + 0x7fff + ((u >> 16) & 1)) >> 16;
    return (unsigned short)r;
}
__device__ inline float bf2f(unsigned short s) {
    return __uint_as_float(((unsigned)s) << 16);
}

__device__ inline int wave_incl_scan(int v, int lane) {
    #pragma unroll
    for (int off = 1; off < 64; off <<= 1) {
        int t = __shfl_up(v, off);
        if (lane >= off) v += t;
    }
    return v;
}

// exclusive scan of one value per thread across a 256-thread block
__device__ inline int block256_excl_scan(int v, int tid, int* ws4) {
    int lane = tid & 63, wv = tid >> 6;
    int incl = wave_incl_scan(v, lane);
    if (lane == 63) ws4[wv] = incl;
    __syncthreads();
    if (tid == 0) {
        int run = 0;
        #pragma unroll
        for (int i = 0; i < 4; i++) { int t = ws4[i]; ws4[i] = run; run += t; }
    }
    __syncthreads();
    return incl + ws4[wv] - v;
}

// ---------------- CSR build ----------------

__global__ void degree_kernel(const int* __restrict__ ei, int* __restrict__ deg) {
    int i = blockIdx.x * blockDim.x + threadIdx.x;
    if (i < EE) atomicAdd(&deg[ei[EE + i]], 1);
}

// per-block sums of deg
__global__ void deg_partial_kernel(const int* __restrict__ deg, int* __restrict__ bsum) {
    __shared__ int ws4[4];
    int tid = threadIdx.x;
    int idx = blockIdx.x * 256 + tid;
    int d = (idx < NN) ? deg[idx] : 0;
    int lane = tid & 63, wv = tid >> 6;
    int s = d;
    #pragma unroll
    for (int off = 32; off; off >>= 1) s += __shfl_down(s, off);
    if (lane == 0) ws4[wv] = s;
    __syncthreads();
    if (tid == 0) bsum[blockIdx.x] = ws4[0] + ws4[1] + ws4[2] + ws4[3];
}

// single 256-thread block: exclusive scan of the 196 block sums
__global__ void scanb_kernel(const int* __restrict__ bsum, int* __restrict__ boff,
                             int* __restrict__ row_ptr) {
    __shared__ int ws4[4];
    int tid = threadIdx.x;
    int v = (tid < SCAN_BLOCKS) ? bsum[tid] : 0;
    int excl = block256_excl_scan(v, tid, ws4);
    if (tid < SCAN_BLOCKS) boff[tid] = excl;
    if (tid == 255) row_ptr[NN] = excl + v;   // == EE
}

// per-block exclusive scan + global offset -> row_ptr, cursor
__global__ void fill_kernel(const int* __restrict__ deg, const int* __restrict__ boff,
                            int* __restrict__ row_ptr, int* __restrict__ cursor) {
    __shared__ int ws4[4];
    int tid = threadIdx.x;
    int idx = blockIdx.x * 256 + tid;
    int d = (idx < NN) ? deg[idx] : 0;
    int excl = block256_excl_scan(d, tid, ws4) + boff[blockIdx.x];
    if (idx < NN) { row_ptr[idx] = excl; cursor[idx] = excl; }
}

__global__ void scatter_kernel(const int* __restrict__ ei, int* __restrict__ cursor,
                               int* __restrict__ csr_src) {
    int i = blockIdx.x * blockDim.x + threadIdx.x;
    if (i < EE) {
        int d = ei[EE + i];
        int pos = atomicAdd(&cursor[d], 1);
        csr_src[pos] = ei[i];
    }
}

// ---------------- fp32 tiled GEMM: C[M,N] = A[M,K] @ B[K,N] (+ bf16 copy) ----------------
template<int BM, int BN>
__global__ __launch_bounds__(256, 2) void gemm_t(const float* __restrict__ A,
                                                 const float* __restrict__ B,
                                                 float* __restrict__ C,
                                                 unsigned short* __restrict__ Cb,
                                                 int M, int N, int K) {
    constexpr int BK = 16;
    constexpr int TM = BM / 16;
    constexpr int TN = BN / 16;
    __shared__ float As[BK][BM + 4];
    __shared__ float Bs[BK][BN + 4];
    int tid = threadIdx.x;
    int tx = tid & 15, ty = tid >> 4;
    int bm = blockIdx.y * BM, bn = blockIdx.x * BN;
    float acc[TM][TN] = {};
    for (int k0 = 0; k0 < K; k0 += BK) {
        #pragma unroll
        for (int i = 0; i < BM * BK / 256; i++) {
            int idx = tid + i * 256;
            int c = idx & 15, r = idx >> 4;
            int row = bm + r;
            As[c][r] = (row < M) ? A[(size_t)row * K + k0 + c] : 0.f;
        }
        #pragma unroll
        for (int i = 0; i < BN * BK / 256; i++) {
            int idx = tid + i * 256;
            int r = idx / BN, c = idx % BN;
            Bs[r][c] = B[(size_t)(k0 + r) * N + bn + c];
        }
        __syncthreads();
        #pragma unroll
        for (int k = 0; k < BK; k++) {
            float a[TM], b[TN];
            #pragma unroll
            for (int i = 0; i < TM; i += 4)
                *(float4*)&a[i] = *(const float4*)&As[k][ty * TM + i];
            #pragma unroll
            for (int j = 0; j < TN; j += 4)
                *(float4*)&b[j] = *(const float4*)&Bs[k][tx * TN + j];
            #pragma unroll
            for (int i = 0; i < TM; i++)
                #pragma unroll
                for (int j = 0; j < TN; j++)
                    acc[i][j] += a[i] * b[j];
        }
        __syncthreads();
    }
    #pragma unroll
    for (int i = 0; i < TM; i++) {
        int row = bm + ty * TM + i;
        if (row < M) {
            #pragma unroll
            for (int j = 0; j < TN; j += 4) {
                float4 v = make_float4(acc[i][j], acc[i][j + 1], acc[i][j + 2], acc[i][j + 3]);
                *(float4*)&C[(size_t)row * N + bn + tx * TN + j] = v;
                ushort4 bv;
                bv.x = f2bf(v.x); bv.y = f2bf(v.y); bv.z = f2bf(v.z); bv.w = f2bf(v.w);
                *(ushort4*)&Cb[(size_t)row * N + bn + tx * TN + j] = bv;
            }
        }
    }
}

// ---------------- attention logits (fp32 features) ----------------
__global__ void alpha1_kernel(const float* __restrict__ h1, const float* __restrict__ a_src,
                              const float* __restrict__ a_dst, float* __restrict__ as_out,
                              float* __restrict__ ad_out) {
    int n = blockIdx.x;
    int tid = threadIdx.x;
    int head = tid >> 6, lane = tid & 63;
    float v = h1[(size_t)n * 256 + tid];
    float ps = v * a_src[tid];
    float pd = v * a_dst[tid];
    #pragma unroll
    for (int off = 32; off; off >>= 1) {
        ps += __shfl_down(ps, off);
        pd += __shfl_down(pd, off);
    }
    if (lane == 0) {
        as_out[n * 4 + head] = ps;
        ad_out[n * 4 + head] = pd;
    }
}

__global__ void alpha2_kernel(const float* __restrict__ g, const float* __restrict__ a_src,
                              const float* __restrict__ a_dst, float* __restrict__ as_out,
                              float* __restrict__ ad_out) {
    int tid = threadIdx.x;
    int wv = tid >> 6, lane = tid & 63;
    int n = blockIdx.x * 4 + wv;
    if (n >= NN) return;
    float v = g[(size_t)n * 64 + lane];
    float ps = v * a_src[lane];
    float pd = v * a_dst[lane];
    #pragma unroll
    for (int off = 32; off; off >>= 1) {
        ps += __shfl_down(ps, off);
        pd += __shfl_down(pd, off);
    }
    if (lane == 0) {
        as_out[n] = ps;
        ad_out[n] = pd;
    }
}

// ---------------- layer-1 aggregation: wave = node, lane = 4 channels (bf16 gather) ----------------
__global__ __launch_bounds__(256) void agg1_kernel(
        const unsigned short* __restrict__ h1b, const int* __restrict__ row_ptr,
        const int* __restrict__ csr_src, const float* __restrict__ as,
        const float* __restrict__ ad, const float* __restrict__ b1,
        float* __restrict__ h2, unsigned short* __restrict__ h2b) {
    __shared__ int   ssrc[4][64];
    __shared__ float wch[4][64][4];
    int tid = threadIdx.x;
    int wv = tid >> 6, lane = tid & 63;
    int n = blockIdx.x * 4 + wv;
    if (n >= NN) return;
    int start = row_ptr[n], end = row_ptr[n + 1];
    float4 adv = ((const float4*)ad)[n];
    int whead = lane >> 4;
    float4 acc = make_float4(0.f, 0.f, 0.f, 0.f);
    float d0 = 0.f, d1 = 0.f, d2 = 0.f, d3 = 0.f;
    for (int c0 = start; c0 < end; c0 += 64) {
        int m = min(64, end - c0);
        if (lane < m) {
            int s = csr_src[c0 + lane];
            ssrc[wv][lane] = s;
            float4 asv = ((const float4*)as)[s];
            float e0 = asv.x + adv.x; e0 = e0 > 0.f ? e0 : 0.2f * e0; float x0 = __expf(e0);
            float e1 = asv.y + adv.y; e1 = e1 > 0.f ? e1 : 0.2f * e1; float x1 = __expf(e1);
            float e2 = asv.z + adv.z; e2 = e2 > 0.f ? e2 : 0.2f * e2; float x2 = __expf(e2);
            float e3 = asv.w + adv.w; e3 = e3 > 0.f ? e3 : 0.2f * e3; float x3 = __expf(e3);
            *(float4*)&wch[wv][lane][0] = make_float4(x0, x1, x2, x3);
            d0 += x0; d1 += x1; d2 += x2; d3 += x3;
        }
        for (int j = 0; j < m; j++) {
            int s = ssrc[wv][j];
            float w = wch[wv][j][whead];
            ushort4 hv = ((const ushort4*)h1b)[(size_t)s * 64 + lane];
            acc.x += bf2f(hv.x) * w; acc.y += bf2f(hv.y) * w;
            acc.z += bf2f(hv.z) * w; acc.w += bf2f(hv.w) * w;
        }
    }
    #pragma unroll
    for (int off = 32; off; off >>= 1) {
        d0 += __shfl_down(d0, off); d1 += __shfl_down(d1, off);
        d2 += __shfl_down(d2, off); d3 += __shfl_down(d3, off);
    }
    d0 = __shfl(d0, 0); d1 = __shfl(d1, 0);
    d2 = __shfl(d2, 0); d3 = __shfl(d3, 0);
    float den = whead == 0 ? d0 : whead == 1 ? d1 : whead == 2 ? d2 : d3;
    float inv = 1.f / (den + 1e-16f);
    float4 bv = ((const float4*)b1)[lane];
    float4 r;
    r.x = acc.x * inv + bv.x; r.y = acc.y * inv + bv.y;
    r.z = acc.z * inv + bv.z; r.w = acc.w * inv + bv.w;
    r.x = r.x > 0.f ? r.x : expm1f(r.x);
    r.y = r.y > 0.f ? r.y : expm1f(r.y);
    r.z = r.z > 0.f ? r.z : expm1f(r.z);
    r.w = r.w > 0.f ? r.w : expm1f(r.w);
    ((float4*)h2)[(size_t)n * 64 + lane] = r;
}

// ---------------- layer-2 aggregation: wave = node, lane = channel (bf16 gather) ----------------
__global__ __launch_bounds__(256) void agg2_kernel(
        const unsigned short* __restrict__ g2b, const int* __restrict__ row_ptr,
        const int* __restrict__ csr_src, const float* __restrict__ as,
        const float* __restrict__ ad, const float* __restrict__ b2,
        float* __restrict__ out) {
    __shared__ int   ssrc[4][64];
    __shared__ float wts[4][64];
    int tid = threadIdx.x;
    int wv = tid >> 6, lane = tid & 63;
    int n = blockIdx.x * 4 + wv;
    if (n >= NN) return;
    int start = row_ptr[n], end = row_ptr[n + 1];
    float adv = ad[n];
    float acc = 0.f;
    float den = 0.f;
    for (int c0 = start; c0 < end; c0 += 64) {
        int m = min(64, end - c0);
        if (lane < m) {
            int s = csr_src[c0 + lane];
            ssrc[wv][lane] = s;
            float e = as[s] + adv;
            e = e > 0.f ? e : 0.2f * e;
            float x = __expf(e);
            wts[wv][lane] = x;
            den += x;
        }
        for (int j = 0; j < m; j++) {
            int s = ssrc[wv][j];
            float w = wts[wv][j];
            acc += bf2f(g2b[(size_t)s * 64 + lane]) * w;
        }
    }
    #pragma unroll
    for (int off = 32; off; off >>= 1) den += __shfl_down(den, off);
    den = __shfl(den, 0);
    float inv = 1.f / (den + 1e-16f);
    float r = acc * inv + b2[lane];
    out[(size_t)n * 64 + lane] = r > 0.f ? r : expm1f(r);
}

// ---------------- launch ----------------

extern "C" void kernel_launch(void* const* d_in, const int* in_sizes, int n_in,
                              void* d_out, int out_size, void* d_ws, size_t ws_size,
                              hipStream_t stream) {
    const float* x      = (const float*)d_in[0];
    const int*   ei     = (const int*)d_in[1];
    const float* W1     = (const float*)d_in[2];
    const float* a_src1 = (const float*)d_in[3];
    const float* a_dst1 = (const float*)d_in[4];
    const float* b1     = (const float*)d_in[5];
    const float* W2     = (const float*)d_in[6];
    const float* a_src2 = (const float*)d_in[7];
    const float* a_dst2 = (const float*)d_in[8];
    const float* b2     = (const float*)d_in[9];
    float* out = (float*)d_out;

    char* base = (char*)d_ws;
    size_t off = 0;
    auto alloc = [&](size_t bytes) -> void* {
        void* p = base + off;
        off = (off + bytes + 255) & ~(size_t)255;
        return p;
    };
    int*   deg     = (int*)alloc(NN * sizeof(int));
    int*   bsum    = (int*)alloc(SCAN_BLOCKS * sizeof(int));
    int*   boff    = (int*)alloc(SCAN_BLOCKS * sizeof(int));
    int*   row_ptr = (int*)alloc((NN + 1) * sizeof(int));
    int*   cursor  = (int*)alloc(NN * sizeof(int));
    int*   csr_src = (int*)alloc(EE * sizeof(int));
    float* h1      = (float*)alloc((size_t)NN * 256 * sizeof(float));
    unsigned short* h1b = (unsigned short*)alloc((size_t)NN * 256 * sizeof(unsigned short));
    float* as1     = (float*)alloc((size_t)NN * 4 * sizeof(float));
    float* ad1     = (float*)alloc((size_t)NN * 4 * sizeof(float));
    float* h2      = (float*)alloc((size_t)NN * 256 * sizeof(float));
    unsigned short* h2b = (unsigned short*)alloc((size_t)NN * 256 * sizeof(unsigned short));
    float* g2      = (float*)alloc((size_t)NN * 64 * sizeof(float));
    unsigned short* g2b = (unsigned short*)alloc((size_t)NN * 64 * sizeof(unsigned short));
    float* as2     = (float*)alloc((size_t)NN * sizeof(float));
    float* ad2     = (float*)alloc((size_t)NN * sizeof(float));

    hipMemsetAsync(deg, 0, NN * sizeof(int), stream);

    int eblocks = (EE + 255) / 256;
    degree_kernel<<<eblocks, 256, 0, stream>>>(ei, deg);
    deg_partial_kernel<<<SCAN_BLOCKS, 256, 0, stream>>>(deg, bsum);
    scanb_kernel<<<1, 256, 0, stream>>>(bsum, boff, row_ptr);
    fill_kernel<<<SCAN_BLOCKS, 256, 0, stream>>>(deg, boff, row_ptr, cursor);
    scatter_kernel<<<eblocks, 256, 0, stream>>>(ei, cursor, csr_src);

    // layer 1: h1 = x @ W1   (50000x128 @ 128x256)
    {
        dim3 g((HEADS * HID) / 128, (NN + 127) / 128);
        gemm_t<128, 128><<<g, 256, 0, stream>>>(x, W1, h1, h1b, NN, HEADS * HID, IN_C);
    }
    alpha1_kernel<<<NN, 256, 0, stream>>>(h1, a_src1, a_dst1, as1, ad1);
    agg1_kernel<<<(NN + 3) / 4, 256, 0, stream>>>(h1b, row_ptr, csr_src, as1, ad1, b1, h2, h2b);

    // layer 2: g2 = h2 @ W2  (50000x256 @ 256x64)
    {
        dim3 g(HID / 64, (NN + 127) / 128);
        gemm_t<128, 64><<<g, 256, 0, stream>>>(h2, W2, g2, g2b, NN, HID, HEADS * HID);
    }
    alpha2_kernel<<<(NN + 3) / 4, 256, 0, stream>>>(g2, a_src2, a_dst2, as2, ad2);
    agg2_kernel<<<(NN + 3) / 4, 256, 0, stream>>>(g2b, row_ptr, csr_src, as2, ad2, b2, out);
}

// Round 4
// 354.068 us; speedup vs baseline: 1.9588x; 1.3189x over previous
//
#include <hip/hip_runtime.h>
#include <math.h>

#define NN 50000
#define EE 800000
#define IN_C 128
#define HID 64
#define HEADS 4
#define SCAN_BLOCKS ((NN + 255) / 256)   // 196

typedef __attribute__((ext_vector_type(8))) short bf16x8;
typedef __attribute__((ext_vector_type(4))) float f32x4;

// ---------------- helpers ----------------

__device__ inline unsigned short f2bf(float f) {       // fp32 -> bf16 RNE
    unsigned u = __float_as_uint(f);
    return (unsigned short)((u + 0x7fff + ((u >> 16) & 1)) >> 16);
}
__device__ inline float bf2f(unsigned short s) {
    return __uint_as_float(((unsigned)s) << 16);
}

__device__ inline int wave_incl_scan(int v, int lane) {
    #pragma unroll
    for (int off = 1; off < 64; off <<= 1) {
        int t = __shfl_up(v, off);
        if (lane >= off) v += t;
    }
    return v;
}

__device__ inline int block256_excl_scan(int v, int tid, int* ws4) {
    int lane = tid & 63, wv = tid >> 6;
    int incl = wave_incl_scan(v, lane);
    if (lane == 63) ws4[wv] = incl;
    __syncthreads();
    if (tid == 0) {
        int run = 0;
        #pragma unroll
        for (int i = 0; i < 4; i++) { int t = ws4[i]; ws4[i] = run; run += t; }
    }
    __syncthreads();
    return incl + ws4[wv] - v;
}

// ---------------- CSR build ----------------

__global__ void degree_kernel(const int* __restrict__ ei, int* __restrict__ deg) {
    int i = blockIdx.x * blockDim.x + threadIdx.x;
    if (i < EE) atomicAdd(&deg[ei[EE + i]], 1);
}

__global__ void deg_partial_kernel(const int* __restrict__ deg, int* __restrict__ bsum) {
    __shared__ int ws4[4];
    int tid = threadIdx.x;
    int idx = blockIdx.x * 256 + tid;
    int d = (idx < NN) ? deg[idx] : 0;
    int lane = tid & 63, wv = tid >> 6;
    int s = d;
    #pragma unroll
    for (int off = 32; off; off >>= 1) s += __shfl_down(s, off);
    if (lane == 0) ws4[wv] = s;
    __syncthreads();
    if (tid == 0) bsum[blockIdx.x] = ws4[0] + ws4[1] + ws4[2] + ws4[3];
}

__global__ void scanb_kernel(const int* __restrict__ bsum, int* __restrict__ boff,
                             int* __restrict__ row_ptr) {
    __shared__ int ws4[4];
    int tid = threadIdx.x;
    int v = (tid < SCAN_BLOCKS) ? bsum[tid] : 0;
    int excl = block256_excl_scan(v, tid, ws4);
    if (tid < SCAN_BLOCKS) boff[tid] = excl;
    if (tid == 255) row_ptr[NN] = excl + v;   // == EE
}

__global__ void fill_kernel(const int* __restrict__ deg, const int* __restrict__ boff,
                            int* __restrict__ row_ptr, int* __restrict__ cursor) {
    __shared__ int ws4[4];
    int tid = threadIdx.x;
    int idx = blockIdx.x * 256 + tid;
    int d = (idx < NN) ? deg[idx] : 0;
    int excl = block256_excl_scan(d, tid, ws4) + boff[blockIdx.x];
    if (idx < NN) { row_ptr[idx] = excl; cursor[idx] = excl; }
}

__global__ void scatter_kernel(const int* __restrict__ ei, int* __restrict__ cursor,
                               int* __restrict__ csr_src) {
    int i = blockIdx.x * blockDim.x + threadIdx.x;
    if (i < EE) {
        int d = ei[EE + i];
        int pos = atomicAdd(&cursor[d], 1);
        csr_src[pos] = ei[i];
    }
}

// ---------------- split / transpose precomputes ----------------

// x [NN][128] fp32 -> xhi,xlo [NN][128] bf16. grid*256 == NN*32 exactly.
__global__ void split_x_kernel(const float* __restrict__ x, unsigned short* __restrict__ xhi,
                               unsigned short* __restrict__ xlo) {
    int i = blockIdx.x * 256 + threadIdx.x;      // float4 index
    float4 v = ((const float4*)x)[i];
    ushort4 h, l;
    h.x = f2bf(v.x); l.x = f2bf(v.x - bf2f(h.x));
    h.y = f2bf(v.y); l.y = f2bf(v.y - bf2f(h.y));
    h.z = f2bf(v.z); l.z = f2bf(v.z - bf2f(h.z));
    h.w = f2bf(v.w); l.w = f2bf(v.w - bf2f(h.w));
    ((ushort4*)xhi)[i] = h;
    ((ushort4*)xlo)[i] = l;
}

// W [R][C] fp32 -> hiT,loT [C][R] bf16 (transposed for k-contiguous B fragments)
template<int R, int C>
__global__ void tsplit_kernel(const float* __restrict__ W,
                              unsigned short* __restrict__ hiT,
                              unsigned short* __restrict__ loT) {
    int idx = blockIdx.x * 256 + threadIdx.x;
    if (idx >= R * C) return;
    int r = idx / C, c = idx % C;
    float v = W[idx];
    unsigned short h = f2bf(v);
    unsigned short l = f2bf(v - bf2f(h));
    hiT[c * R + r] = h;
    loT[c * R + r] = l;
}

// ---------------- layer-1 MFMA GEMM + fused alpha ----------------
// h1 = x @ W1 (50000x128 @ 128x256), split-bf16 3-product.
// Block = 4 waves; wave w computes rows [brow,brow+32) x cols [w*64,(w+1)*64) (= head w).
// Writes h1b (bf16) and as1/ad1 (fp32 logits) -- no fp32 h1, no LDS, no barriers.
__global__ __launch_bounds__(256) void gemm1_mfma(
        const unsigned short* __restrict__ xhi, const unsigned short* __restrict__ xlo,
        const unsigned short* __restrict__ Bhi, const unsigned short* __restrict__ Blo, // W1T [256][128]
        const float* __restrict__ a_src, const float* __restrict__ a_dst,
        unsigned short* __restrict__ h1b, float* __restrict__ as1, float* __restrict__ ad1) {
    int tid = threadIdx.x;
    int w = tid >> 6, lane = tid & 63;
    int lq = lane >> 4, lr = lane & 15;
    int brow = blockIdx.x * 32;
    f32x4 acc[2][4];
    f32x4 zf = {0.f, 0.f, 0.f, 0.f};
    #pragma unroll
    for (int mi = 0; mi < 2; mi++)
        #pragma unroll
        for (int ni = 0; ni < 4; ni++) acc[mi][ni] = zf;
    int ra = min(brow + lr, NN - 1);          // clamped loads; stores are guarded
    int rb = min(brow + 16 + lr, NN - 1);
    #pragma unroll
    for (int q = 0; q < 4; q++) {             // K = 128 = 4 chunks of 32
        int ko = q * 32 + lq * 8;
        bf16x8 ah0 = *(const bf16x8*)(const void*)(xhi + (size_t)ra * 128 + ko);
        bf16x8 al0 = *(const bf16x8*)(const void*)(xlo + (size_t)ra * 128 + ko);
        bf16x8 ah1 = *(const bf16x8*)(const void*)(xhi + (size_t)rb * 128 + ko);
        bf16x8 al1 = *(const bf16x8*)(const void*)(xlo + (size_t)rb * 128 + ko);
        #pragma unroll
        for (int ni = 0; ni < 4; ni++) {
            size_t bo = (size_t)(w * 64 + ni * 16 + lr) * 128 + ko;
            bf16x8 bh = *(const bf16x8*)(const void*)(Bhi + bo);
            bf16x8 bl = *(const bf16x8*)(const void*)(Blo + bo);
            acc[0][ni] = __builtin_amdgcn_mfma_f32_16x16x32_bf16(al0, bh, acc[0][ni], 0, 0, 0);
            acc[0][ni] = __builtin_amdgcn_mfma_f32_16x16x32_bf16(ah0, bl, acc[0][ni], 0, 0, 0);
            acc[0][ni] = __builtin_amdgcn_mfma_f32_16x16x32_bf16(ah0, bh, acc[0][ni], 0, 0, 0);
            acc[1][ni] = __builtin_amdgcn_mfma_f32_16x16x32_bf16(al1, bh, acc[1][ni], 0, 0, 0);
            acc[1][ni] = __builtin_amdgcn_mfma_f32_16x16x32_bf16(ah1, bl, acc[1][ni], 0, 0, 0);
            acc[1][ni] = __builtin_amdgcn_mfma_f32_16x16x32_bf16(ah1, bh, acc[1][ni], 0, 0, 0);
        }
    }
    // epilogue: alpha logits (full 64-col dot for head w) + bf16 h1 store
    float asv[4], adv[4];
    #pragma unroll
    for (int ni = 0; ni < 4; ni++) {
        asv[ni] = a_src[w * 64 + ni * 16 + lr];
        adv[ni] = a_dst[w * 64 + ni * 16 + lr];
    }
    #pragma unroll
    for (int mi = 0; mi < 2; mi++) {
        f32x4 ps = zf, pd = zf;
        #pragma unroll
        for (int ni = 0; ni < 4; ni++)
            #pragma unroll
            for (int r = 0; r < 4; r++) {
                ps[r] += acc[mi][ni][r] * asv[ni];
                pd[r] += acc[mi][ni][r] * adv[ni];
            }
        #pragma unroll
        for (int m = 1; m < 16; m <<= 1)
            #pragma unroll
            for (int r = 0; r < 4; r++) {
                ps[r] += __shfl_xor(ps[r], m);
                pd[r] += __shfl_xor(pd[r], m);
            }
        #pragma unroll
        for (int r = 0; r < 4; r++) {
            int n = brow + mi * 16 + lq * 4 + r;
            if (lr == 0 && n < NN) { as1[n * 4 + w] = ps[r]; ad1[n * 4 + w] = pd[r]; }
        }
        #pragma unroll
        for (int ni = 0; ni < 4; ni++)
            #pragma unroll
            for (int r = 0; r < 4; r++) {
                int n = brow + mi * 16 + lq * 4 + r;
                if (n < NN)
                    h1b[(size_t)n * 256 + w * 64 + ni * 16 + lr] = f2bf(acc[mi][ni][r]);
            }
    }
}

// ---------------- layer-2 MFMA GEMM + fused alpha ----------------
// g2 = h2 @ W2 (50000x256 @ 256x64). A = h2 split pair from agg1. Writes g2b + as2/ad2.
__global__ __launch_bounds__(256) void gemm2_mfma(
        const unsigned short* __restrict__ Ahi, const unsigned short* __restrict__ Alo,
        const unsigned short* __restrict__ Bhi, const unsigned short* __restrict__ Blo, // W2T [64][256]
        const float* __restrict__ a_src, const float* __restrict__ a_dst,
        unsigned short* __restrict__ g2b, float* __restrict__ as2, float* __restrict__ ad2) {
    int tid = threadIdx.x;
    int w = tid >> 6, lane = tid & 63;
    int lq = lane >> 4, lr = lane & 15;
    int wrow = blockIdx.x * 128 + w * 32;     // 4 waves stacked in M, all cover N=64
    f32x4 acc[2][4];
    f32x4 zf = {0.f, 0.f, 0.f, 0.f};
    #pragma unroll
    for (int mi = 0; mi < 2; mi++)
        #pragma unroll
        for (int ni = 0; ni < 4; ni++) acc[mi][ni] = zf;
    int ra = min(wrow + lr, NN - 1);
    int rb = min(wrow + 16 + lr, NN - 1);
    #pragma unroll
    for (int q = 0; q < 8; q++) {             // K = 256 = 8 chunks of 32
        int ko = q * 32 + lq * 8;
        bf16x8 ah0 = *(const bf16x8*)(const void*)(Ahi + (size_t)ra * 256 + ko);
        bf16x8 al0 = *(const bf16x8*)(const void*)(Alo + (size_t)ra * 256 + ko);
        bf16x8 ah1 = *(const bf16x8*)(const void*)(Ahi + (size_t)rb * 256 + ko);
        bf16x8 al1 = *(const bf16x8*)(const void*)(Alo + (size_t)rb * 256 + ko);
        #pragma unroll
        for (int ni = 0; ni < 4; ni++) {
            size_t bo = (size_t)(ni * 16 + lr) * 256 + ko;
            bf16x8 bh = *(const bf16x8*)(const void*)(Bhi + bo);
            bf16x8 bl = *(const bf16x8*)(const void*)(Blo + bo);
            acc[0][ni] = __builtin_amdgcn_mfma_f32_16x16x32_bf16(al0, bh, acc[0][ni], 0, 0, 0);
            acc[0][ni] = __builtin_amdgcn_mfma_f32_16x16x32_bf16(ah0, bl, acc[0][ni], 0, 0, 0);
            acc[0][ni] = __builtin_amdgcn_mfma_f32_16x16x32_bf16(ah0, bh, acc[0][ni], 0, 0, 0);
            acc[1][ni] = __builtin_amdgcn_mfma_f32_16x16x32_bf16(al1, bh, acc[1][ni], 0, 0, 0);
            acc[1][ni] = __builtin_amdgcn_mfma_f32_16x16x32_bf16(ah1, bl, acc[1][ni], 0, 0, 0);
            acc[1][ni] = __builtin_amdgcn_mfma_f32_16x16x32_bf16(ah1, bh, acc[1][ni], 0, 0, 0);
        }
    }
    float asv[4], adv[4];
    #pragma unroll
    for (int ni = 0; ni < 4; ni++) {
        asv[ni] = a_src[ni * 16 + lr];
        adv[ni] = a_dst[ni * 16 + lr];
    }
    #pragma unroll
    for (int mi = 0; mi < 2; mi++) {
        f32x4 ps = zf, pd = zf;
        #pragma unroll
        for (int ni = 0; ni < 4; ni++)
            #pragma unroll
            for (int r = 0; r < 4; r++) {
                ps[r] += acc[mi][ni][r] * asv[ni];
                pd[r] += acc[mi][ni][r] * adv[ni];
            }
        #pragma unroll
        for (int m = 1; m < 16; m <<= 1)
            #pragma unroll
            for (int r = 0; r < 4; r++) {
                ps[r] += __shfl_xor(ps[r], m);
                pd[r] += __shfl_xor(pd[r], m);
            }
        #pragma unroll
        for (int r = 0; r < 4; r++) {
            int n = wrow + mi * 16 + lq * 4 + r;
            if (lr == 0 && n < NN) { as2[n] = ps[r]; ad2[n] = pd[r]; }
        }
        #pragma unroll
        for (int ni = 0; ni < 4; ni++)
            #pragma unroll
            for (int r = 0; r < 4; r++) {
                int n = wrow + mi * 16 + lq * 4 + r;
                if (n < NN)
                    g2b[(size_t)n * 64 + ni * 16 + lr] = f2bf(acc[mi][ni][r]);
            }
    }
}

// ---------------- layer-1 aggregation: wave = node, lane = 4 channels (bf16 gather) ----------------
// outputs h2 as split bf16 pair (hi+lo) for the layer-2 MFMA GEMM
__global__ __launch_bounds__(256) void agg1_kernel(
        const unsigned short* __restrict__ h1b, const int* __restrict__ row_ptr,
        const int* __restrict__ csr_src, const float* __restrict__ as,
        const float* __restrict__ ad, const float* __restrict__ b1,
        unsigned short* __restrict__ h2hi, unsigned short* __restrict__ h2lo) {
    __shared__ int   ssrc[4][64];
    __shared__ float wch[4][64][4];
    int tid = threadIdx.x;
    int wv = tid >> 6, lane = tid & 63;
    int n = blockIdx.x * 4 + wv;
    if (n >= NN) return;
    int start = row_ptr[n], end = row_ptr[n + 1];
    float4 adv = ((const float4*)ad)[n];
    int whead = lane >> 4;
    float4 acc = make_float4(0.f, 0.f, 0.f, 0.f);
    float d0 = 0.f, d1 = 0.f, d2 = 0.f, d3 = 0.f;
    for (int c0 = start; c0 < end; c0 += 64) {
        int m = min(64, end - c0);
        if (lane < m) {
            int s = csr_src[c0 + lane];
            ssrc[wv][lane] = s;
            float4 asv = ((const float4*)as)[s];
            float e0 = asv.x + adv.x; e0 = e0 > 0.f ? e0 : 0.2f * e0; float x0 = __expf(e0);
            float e1 = asv.y + adv.y; e1 = e1 > 0.f ? e1 : 0.2f * e1; float x1 = __expf(e1);
            float e2 = asv.z + adv.z; e2 = e2 > 0.f ? e2 : 0.2f * e2; float x2 = __expf(e2);
            float e3 = asv.w + adv.w; e3 = e3 > 0.f ? e3 : 0.2f * e3; float x3 = __expf(e3);
            *(float4*)&wch[wv][lane][0] = make_float4(x0, x1, x2, x3);
            d0 += x0; d1 += x1; d2 += x2; d3 += x3;
        }
        for (int j = 0; j < m; j++) {
            int s = ssrc[wv][j];
            float w = wch[wv][j][whead];
            ushort4 hv = ((const ushort4*)h1b)[(size_t)s * 64 + lane];
            acc.x += bf2f(hv.x) * w; acc.y += bf2f(hv.y) * w;
            acc.z += bf2f(hv.z) * w; acc.w += bf2f(hv.w) * w;
        }
    }
    #pragma unroll
    for (int off = 32; off; off >>= 1) {
        d0 += __shfl_down(d0, off); d1 += __shfl_down(d1, off);
        d2 += __shfl_down(d2, off); d3 += __shfl_down(d3, off);
    }
    d0 = __shfl(d0, 0); d1 = __shfl(d1, 0);
    d2 = __shfl(d2, 0); d3 = __shfl(d3, 0);
    float den = whead == 0 ? d0 : whead == 1 ? d1 : whead == 2 ? d2 : d3;
    float inv = 1.f / (den + 1e-16f);
    float4 bv = ((const float4*)b1)[lane];
    float4 r;
    r.x = acc.x * inv + bv.x; r.y = acc.y * inv + bv.y;
    r.z = acc.z * inv + bv.z; r.w = acc.w * inv + bv.w;
    r.x = r.x > 0.f ? r.x : expm1f(r.x);
    r.y = r.y > 0.f ? r.y : expm1f(r.y);
    r.z = r.z > 0.f ? r.z : expm1f(r.z);
    r.w = r.w > 0.f ? r.w : expm1f(r.w);
    ushort4 hi4, lo4;
    hi4.x = f2bf(r.x); lo4.x = f2bf(r.x - bf2f(hi4.x));
    hi4.y = f2bf(r.y); lo4.y = f2bf(r.y - bf2f(hi4.y));
    hi4.z = f2bf(r.z); lo4.z = f2bf(r.z - bf2f(hi4.z));
    hi4.w = f2bf(r.w); lo4.w = f2bf(r.w - bf2f(hi4.w));
    ((ushort4*)h2hi)[(size_t)n * 64 + lane] = hi4;
    ((ushort4*)h2lo)[(size_t)n * 64 + lane] = lo4;
}

// ---------------- layer-2 aggregation: wave = node, lane = channel (bf16 gather) ----------------
__global__ __launch_bounds__(256) void agg2_kernel(
        const unsigned short* __restrict__ g2b, const int* __restrict__ row_ptr,
        const int* __restrict__ csr_src, const float* __restrict__ as,
        const float* __restrict__ ad, const float* __restrict__ b2,
        float* __restrict__ out) {
    __shared__ int   ssrc[4][64];
    __shared__ float wts[4][64];
    int tid = threadIdx.x;
    int wv = tid >> 6, lane = tid & 63;
    int n = blockIdx.x * 4 + wv;
    if (n >= NN) return;
    int start = row_ptr[n], end = row_ptr[n + 1];
    float adv = ad[n];
    float acc = 0.f;
    float den = 0.f;
    for (int c0 = start; c0 < end; c0 += 64) {
        int m = min(64, end - c0);
        if (lane < m) {
            int s = csr_src[c0 + lane];
            ssrc[wv][lane] = s;
            float e = as[s] + adv;
            e = e > 0.f ? e : 0.2f * e;
            float x = __expf(e);
            wts[wv][lane] = x;
            den += x;
        }
        for (int j = 0; j < m; j++) {
            int s = ssrc[wv][j];
            float w = wts[wv][j];
            acc += bf2f(g2b[(size_t)s * 64 + lane]) * w;
        }
    }
    #pragma unroll
    for (int off = 32; off; off >>= 1) den += __shfl_down(den, off);
    den = __shfl(den, 0);
    float inv = 1.f / (den + 1e-16f);
    float r = acc * inv + b2[lane];
    out[(size_t)n * 64 + lane] = r > 0.f ? r : expm1f(r);
}

// ---------------- launch ----------------

extern "C" void kernel_launch(void* const* d_in, const int* in_sizes, int n_in,
                              void* d_out, int out_size, void* d_ws, size_t ws_size,
                              hipStream_t stream) {
    const float* x      = (const float*)d_in[0];
    const int*   ei     = (const int*)d_in[1];
    const float* W1     = (const float*)d_in[2];
    const float* a_src1 = (const float*)d_in[3];
    const float* a_dst1 = (const float*)d_in[4];
    const float* b1     = (const float*)d_in[5];
    const float* W2     = (const float*)d_in[6];
    const float* a_src2 = (const float*)d_in[7];
    const float* a_dst2 = (const float*)d_in[8];
    const float* b2     = (const float*)d_in[9];
    float* out = (float*)d_out;

    char* base = (char*)d_ws;
    size_t off = 0;
    auto alloc = [&](size_t bytes) -> void* {
        void* p = base + off;
        off = (off + bytes + 255) & ~(size_t)255;
        return p;
    };
    int*   deg     = (int*)alloc(NN * sizeof(int));
    int*   bsum    = (int*)alloc(SCAN_BLOCKS * sizeof(int));
    int*   boff    = (int*)alloc(SCAN_BLOCKS * sizeof(int));
    int*   row_ptr = (int*)alloc((NN + 1) * sizeof(int));
    int*   cursor  = (int*)alloc(NN * sizeof(int));
    int*   csr_src = (int*)alloc(EE * sizeof(int));
    unsigned short* xhi   = (unsigned short*)alloc((size_t)NN * 128 * 2);
    unsigned short* xlo   = (unsigned short*)alloc((size_t)NN * 128 * 2);
    unsigned short* W1Thi = (unsigned short*)alloc(256 * 128 * 2);
    unsigned short* W1Tlo = (unsigned short*)alloc(256 * 128 * 2);
    unsigned short* W2Thi = (unsigned short*)alloc(64 * 256 * 2);
    unsigned short* W2Tlo = (unsigned short*)alloc(64 * 256 * 2);
    unsigned short* h1b   = (unsigned short*)alloc((size_t)NN * 256 * 2);
    float* as1     = (float*)alloc((size_t)NN * 4 * sizeof(float));
    float* ad1     = (float*)alloc((size_t)NN * 4 * sizeof(float));
    unsigned short* h2hi  = (unsigned short*)alloc((size_t)NN * 256 * 2);
    unsigned short* h2lo  = (unsigned short*)alloc((size_t)NN * 256 * 2);
    unsigned short* g2b   = (unsigned short*)alloc((size_t)NN * 64 * 2);
    float* as2     = (float*)alloc((size_t)NN * sizeof(float));
    float* ad2     = (float*)alloc((size_t)NN * sizeof(float));

    hipMemsetAsync(deg, 0, NN * sizeof(int), stream);

    int eblocks = (EE + 255) / 256;
    degree_kernel<<<eblocks, 256, 0, stream>>>(ei, deg);
    deg_partial_kernel<<<SCAN_BLOCKS, 256, 0, stream>>>(deg, bsum);
    scanb_kernel<<<1, 256, 0, stream>>>(bsum, boff, row_ptr);
    fill_kernel<<<SCAN_BLOCKS, 256, 0, stream>>>(deg, boff, row_ptr, cursor);
    scatter_kernel<<<eblocks, 256, 0, stream>>>(ei, cursor, csr_src);

    // precompute split operands
    split_x_kernel<<<NN * 32 / 256, 256, 0, stream>>>(x, xhi, xlo);
    tsplit_kernel<128, 256><<<(128 * 256 + 255) / 256, 256, 0, stream>>>(W1, W1Thi, W1Tlo);
    tsplit_kernel<256, 64><<<(256 * 64 + 255) / 256, 256, 0, stream>>>(W2, W2Thi, W2Tlo);

    // layer 1
    gemm1_mfma<<<(NN + 31) / 32, 256, 0, stream>>>(xhi, xlo, W1Thi, W1Tlo,
                                                   a_src1, a_dst1, h1b, as1, ad1);
    agg1_kernel<<<(NN + 3) / 4, 256, 0, stream>>>(h1b, row_ptr, csr_src, as1, ad1, b1,
                                                  h2hi, h2lo);

    // layer 2
    gemm2_mfma<<<(NN + 127) / 128, 256, 0, stream>>>(h2hi, h2lo, W2Thi, W2Tlo,
                                                     a_src2, a_dst2, g2b, as2, ad2);
    agg2_kernel<<<(NN + 3) / 4, 256, 0, stream>>>(g2b, row_ptr, csr_src, as2, ad2, b2, out);
}

// Round 5
// 330.791 us; speedup vs baseline: 2.0966x; 1.0704x over previous
//
#include <hip/hip_runtime.h>
#include <math.h>

#define NN 50000
#define EE 800000
#define IN_C 128
#define HID 64
#define HEADS 4
#define SCAN_BLOCKS ((NN + 255) / 256)   // 196
#define EBLOCKS ((EE + 255) / 256)       // 3125

typedef __attribute__((ext_vector_type(8))) short bf16x8;
typedef __attribute__((ext_vector_type(4))) float f32x4;

// ---------------- helpers ----------------

__device__ inline unsigned short f2bf(float f) {       // fp32 -> bf16 RNE
    unsigned u = __float_as_uint(f);
    return (unsigned short)((u + 0x7fff + ((u >> 16) & 1)) >> 16);
}
__device__ inline float bf2f(unsigned short s) {
    return __uint_as_float(((unsigned)s) << 16);
}

__device__ inline int wave_incl_scan(int v, int lane) {
    #pragma unroll
    for (int off = 1; off < 64; off <<= 1) {
        int t = __shfl_up(v, off);
        if (lane >= off) v += t;
    }
    return v;
}

__device__ inline int block256_excl_scan(int v, int tid, int* ws4) {
    int lane = tid & 63, wv = tid >> 6;
    int incl = wave_incl_scan(v, lane);
    if (lane == 63) ws4[wv] = incl;
    __syncthreads();
    if (tid == 0) {
        int run = 0;
        #pragma unroll
        for (int i = 0; i < 4; i++) { int t = ws4[i]; ws4[i] = run; run += t; }
    }
    __syncthreads();
    return incl + ws4[wv] - v;
}

// ---------------- prep: degree histogram + both weight transposes/splits ----------------

__global__ void prep_kernel(const int* __restrict__ ei, int* __restrict__ deg,
                            const float* __restrict__ W1, unsigned short* __restrict__ W1Thi,
                            unsigned short* __restrict__ W1Tlo,
                            const float* __restrict__ W2, unsigned short* __restrict__ W2Thi,
                            unsigned short* __restrict__ W2Tlo) {
    int b = blockIdx.x;
    int tid = threadIdx.x;
    if (b < EBLOCKS) {
        int i = b * 256 + tid;
        if (i < EE) atomicAdd(&deg[ei[EE + i]], 1);
    } else if (b < EBLOCKS + 128) {
        // W1 [128][256] -> W1T [256][128] split
        int idx = (b - EBLOCKS) * 256 + tid;         // < 32768
        int r = idx >> 8, c = idx & 255;
        float v = W1[idx];
        unsigned short h = f2bf(v);
        W1Thi[c * 128 + r] = h;
        W1Tlo[c * 128 + r] = f2bf(v - bf2f(h));
    } else {
        // W2 [256][64] -> W2T [64][256] split
        int idx = (b - EBLOCKS - 128) * 256 + tid;   // < 16384
        int r = idx >> 6, c = idx & 63;
        float v = W2[idx];
        unsigned short h = f2bf(v);
        W2Thi[c * 256 + r] = h;
        W2Tlo[c * 256 + r] = f2bf(v - bf2f(h));
    }
}

// ---------------- CSR build ----------------

__global__ void deg_partial_kernel(const int* __restrict__ deg, int* __restrict__ bsum) {
    __shared__ int ws4[4];
    int tid = threadIdx.x;
    int idx = blockIdx.x * 256 + tid;
    int d = (idx < NN) ? deg[idx] : 0;
    int lane = tid & 63, wv = tid >> 6;
    int s = d;
    #pragma unroll
    for (int off = 32; off; off >>= 1) s += __shfl_down(s, off);
    if (lane == 0) ws4[wv] = s;
    __syncthreads();
    if (tid == 0) bsum[blockIdx.x] = ws4[0] + ws4[1] + ws4[2] + ws4[3];
}

__global__ void scanb_kernel(const int* __restrict__ bsum, int* __restrict__ boff,
                             int* __restrict__ row_ptr) {
    __shared__ int ws4[4];
    int tid = threadIdx.x;
    int v = (tid < SCAN_BLOCKS) ? bsum[tid] : 0;
    int excl = block256_excl_scan(v, tid, ws4);
    if (tid < SCAN_BLOCKS) boff[tid] = excl;
    if (tid == 255) row_ptr[NN] = excl + v;   // == EE
}

__global__ void fill_kernel(const int* __restrict__ deg, const int* __restrict__ boff,
                            int* __restrict__ row_ptr, int* __restrict__ cursor) {
    __shared__ int ws4[4];
    int tid = threadIdx.x;
    int idx = blockIdx.x * 256 + tid;
    int d = (idx < NN) ? deg[idx] : 0;
    int excl = block256_excl_scan(d, tid, ws4) + boff[blockIdx.x];
    if (idx < NN) { row_ptr[idx] = excl; cursor[idx] = excl; }
}

__global__ void scatter_kernel(const int* __restrict__ ei, int* __restrict__ cursor,
                               int* __restrict__ csr_src) {
    int i = blockIdx.x * blockDim.x + threadIdx.x;
    if (i < EE) {
        int d = ei[EE + i];
        int pos = atomicAdd(&cursor[d], 1);
        csr_src[pos] = ei[i];
    }
}

// ---------------- layer-1 MFMA GEMM + fused alpha ----------------
// h1 = x @ W1 (50000x128 @ 128x256). A staged+split in LDS once per block.
__global__ __launch_bounds__(256) void gemm1_mfma(
        const float* __restrict__ x,
        const unsigned short* __restrict__ Bhi, const unsigned short* __restrict__ Blo, // W1T [256][128]
        const float* __restrict__ a_src, const float* __restrict__ a_dst,
        unsigned short* __restrict__ h1b, float* __restrict__ as1, float* __restrict__ ad1) {
    __shared__ unsigned short Ahi[32][136];   // +8 pad: 272B row stride, 2-way max on b128
    __shared__ unsigned short Alo[32][136];
    int tid = threadIdx.x;
    int w = tid >> 6, lane = tid & 63;
    int lq = lane >> 4, lr = lane & 15;
    int brow = blockIdx.x * 32;
    // stage: 32 rows x 128 cols of x, fp32 -> bf16 hi/lo
    {
        int row = tid >> 3;                    // 0..31
        int col0 = (tid & 7) * 16;             // 0,16,..,112
        int gr = min(brow + row, NN - 1);
        #pragma unroll
        for (int i = 0; i < 16; i += 4) {
            float4 v = *(const float4*)(x + (size_t)gr * 128 + col0 + i);
            unsigned short h0 = f2bf(v.x), h1 = f2bf(v.y), h2 = f2bf(v.z), h3 = f2bf(v.w);
            Ahi[row][col0 + i + 0] = h0; Alo[row][col0 + i + 0] = f2bf(v.x - bf2f(h0));
            Ahi[row][col0 + i + 1] = h1; Alo[row][col0 + i + 1] = f2bf(v.y - bf2f(h1));
            Ahi[row][col0 + i + 2] = h2; Alo[row][col0 + i + 2] = f2bf(v.z - bf2f(h2));
            Ahi[row][col0 + i + 3] = h3; Alo[row][col0 + i + 3] = f2bf(v.w - bf2f(h3));
        }
    }
    __syncthreads();
    f32x4 acc[2][4];
    f32x4 zf = {0.f, 0.f, 0.f, 0.f};
    #pragma unroll
    for (int mi = 0; mi < 2; mi++)
        #pragma unroll
        for (int ni = 0; ni < 4; ni++) acc[mi][ni] = zf;
    #pragma unroll
    for (int q = 0; q < 4; q++) {             // K = 128 = 4 chunks of 32
        int ko = q * 32 + lq * 8;
        bf16x8 ah0 = *(const bf16x8*)(const void*)&Ahi[lr][ko];
        bf16x8 al0 = *(const bf16x8*)(const void*)&Alo[lr][ko];
        bf16x8 ah1 = *(const bf16x8*)(const void*)&Ahi[16 + lr][ko];
        bf16x8 al1 = *(const bf16x8*)(const void*)&Alo[16 + lr][ko];
        #pragma unroll
        for (int ni = 0; ni < 4; ni++) {
            size_t bo = (size_t)(w * 64 + ni * 16 + lr) * 128 + ko;
            bf16x8 bh = *(const bf16x8*)(const void*)(Bhi + bo);
            bf16x8 bl = *(const bf16x8*)(const void*)(Blo + bo);
            acc[0][ni] = __builtin_amdgcn_mfma_f32_16x16x32_bf16(al0, bh, acc[0][ni], 0, 0, 0);
            acc[0][ni] = __builtin_amdgcn_mfma_f32_16x16x32_bf16(ah0, bl, acc[0][ni], 0, 0, 0);
            acc[0][ni] = __builtin_amdgcn_mfma_f32_16x16x32_bf16(ah0, bh, acc[0][ni], 0, 0, 0);
            acc[1][ni] = __builtin_amdgcn_mfma_f32_16x16x32_bf16(al1, bh, acc[1][ni], 0, 0, 0);
            acc[1][ni] = __builtin_amdgcn_mfma_f32_16x16x32_bf16(ah1, bl, acc[1][ni], 0, 0, 0);
            acc[1][ni] = __builtin_amdgcn_mfma_f32_16x16x32_bf16(ah1, bh, acc[1][ni], 0, 0, 0);
        }
    }
    // epilogue: alpha logits (full 64-col dot for head w) + bf16 h1 store
    float asv[4], adv[4];
    #pragma unroll
    for (int ni = 0; ni < 4; ni++) {
        asv[ni] = a_src[w * 64 + ni * 16 + lr];
        adv[ni] = a_dst[w * 64 + ni * 16 + lr];
    }
    #pragma unroll
    for (int mi = 0; mi < 2; mi++) {
        f32x4 ps = zf, pd = zf;
        #pragma unroll
        for (int ni = 0; ni < 4; ni++)
            #pragma unroll
            for (int r = 0; r < 4; r++) {
                ps[r] += acc[mi][ni][r] * asv[ni];
                pd[r] += acc[mi][ni][r] * adv[ni];
            }
        #pragma unroll
        for (int m = 1; m < 16; m <<= 1)
            #pragma unroll
            for (int r = 0; r < 4; r++) {
                ps[r] += __shfl_xor(ps[r], m);
                pd[r] += __shfl_xor(pd[r], m);
            }
        #pragma unroll
        for (int r = 0; r < 4; r++) {
            int n = brow + mi * 16 + lq * 4 + r;
            if (lr == 0 && n < NN) { as1[n * 4 + w] = ps[r]; ad1[n * 4 + w] = pd[r]; }
        }
        #pragma unroll
        for (int ni = 0; ni < 4; ni++)
            #pragma unroll
            for (int r = 0; r < 4; r++) {
                int n = brow + mi * 16 + lq * 4 + r;
                if (n < NN)
                    h1b[(size_t)n * 256 + w * 64 + ni * 16 + lr] = f2bf(acc[mi][ni][r]);
            }
    }
}

// ---------------- layer-2 MFMA GEMM + fused alpha ----------------
__global__ __launch_bounds__(256) void gemm2_mfma(
        const unsigned short* __restrict__ Ahi, const unsigned short* __restrict__ Alo,
        const unsigned short* __restrict__ Bhi, const unsigned short* __restrict__ Blo, // W2T [64][256]
        const float* __restrict__ a_src, const float* __restrict__ a_dst,
        unsigned short* __restrict__ g2b, float* __restrict__ as2, float* __restrict__ ad2) {
    int tid = threadIdx.x;
    int w = tid >> 6, lane = tid & 63;
    int lq = lane >> 4, lr = lane & 15;
    int wrow = blockIdx.x * 128 + w * 32;
    f32x4 acc[2][4];
    f32x4 zf = {0.f, 0.f, 0.f, 0.f};
    #pragma unroll
    for (int mi = 0; mi < 2; mi++)
        #pragma unroll
        for (int ni = 0; ni < 4; ni++) acc[mi][ni] = zf;
    int ra = min(wrow + lr, NN - 1);
    int rb = min(wrow + 16 + lr, NN - 1);
    #pragma unroll
    for (int q = 0; q < 8; q++) {             // K = 256 = 8 chunks of 32
        int ko = q * 32 + lq * 8;
        bf16x8 ah0 = *(const bf16x8*)(const void*)(Ahi + (size_t)ra * 256 + ko);
        bf16x8 al0 = *(const bf16x8*)(const void*)(Alo + (size_t)ra * 256 + ko);
        bf16x8 ah1 = *(const bf16x8*)(const void*)(Ahi + (size_t)rb * 256 + ko);
        bf16x8 al1 = *(const bf16x8*)(const void*)(Alo + (size_t)rb * 256 + ko);
        #pragma unroll
        for (int ni = 0; ni < 4; ni++) {
            size_t bo = (size_t)(ni * 16 + lr) * 256 + ko;
            bf16x8 bh = *(const bf16x8*)(const void*)(Bhi + bo);
            bf16x8 bl = *(const bf16x8*)(const void*)(Blo + bo);
            acc[0][ni] = __builtin_amdgcn_mfma_f32_16x16x32_bf16(al0, bh, acc[0][ni], 0, 0, 0);
            acc[0][ni] = __builtin_amdgcn_mfma_f32_16x16x32_bf16(ah0, bl, acc[0][ni], 0, 0, 0);
            acc[0][ni] = __builtin_amdgcn_mfma_f32_16x16x32_bf16(ah0, bh, acc[0][ni], 0, 0, 0);
            acc[1][ni] = __builtin_amdgcn_mfma_f32_16x16x32_bf16(al1, bh, acc[1][ni], 0, 0, 0);
            acc[1][ni] = __builtin_amdgcn_mfma_f32_16x16x32_bf16(ah1, bl, acc[1][ni], 0, 0, 0);
            acc[1][ni] = __builtin_amdgcn_mfma_f32_16x16x32_bf16(ah1, bh, acc[1][ni], 0, 0, 0);
        }
    }
    float asv[4], adv[4];
    #pragma unroll
    for (int ni = 0; ni < 4; ni++) {
        asv[ni] = a_src[ni * 16 + lr];
        adv[ni] = a_dst[ni * 16 + lr];
    }
    #pragma unroll
    for (int mi = 0; mi < 2; mi++) {
        f32x4 ps = zf, pd = zf;
        #pragma unroll
        for (int ni = 0; ni < 4; ni++)
            #pragma unroll
            for (int r = 0; r < 4; r++) {
                ps[r] += acc[mi][ni][r] * asv[ni];
                pd[r] += acc[mi][ni][r] * adv[ni];
            }
        #pragma unroll
        for (int m = 1; m < 16; m <<= 1)
            #pragma unroll
            for (int r = 0; r < 4; r++) {
                ps[r] += __shfl_xor(ps[r], m);
                pd[r] += __shfl_xor(pd[r], m);
            }
        #pragma unroll
        for (int r = 0; r < 4; r++) {
            int n = wrow + mi * 16 + lq * 4 + r;
            if (lr == 0 && n < NN) { as2[n] = ps[r]; ad2[n] = pd[r]; }
        }
        #pragma unroll
        for (int ni = 0; ni < 4; ni++)
            #pragma unroll
            for (int r = 0; r < 4; r++) {
                int n = wrow + mi * 16 + lq * 4 + r;
                if (n < NN)
                    g2b[(size_t)n * 64 + ni * 16 + lr] = f2bf(acc[mi][ni][r]);
            }
    }
}

// ---------------- layer-1 aggregation: wave = node, unroll-4 gather ----------------
__global__ __launch_bounds__(256) void agg1_kernel(
        const unsigned short* __restrict__ h1b, const int* __restrict__ row_ptr,
        const int* __restrict__ csr_src, const float* __restrict__ as,
        const float* __restrict__ ad, const float* __restrict__ b1,
        unsigned short* __restrict__ h2hi, unsigned short* __restrict__ h2lo) {
    __shared__ int   ssrc[4][64];
    __shared__ float wch[4][64][4];
    int tid = threadIdx.x;
    int wv = tid >> 6, lane = tid & 63;
    int n = blockIdx.x * 4 + wv;
    if (n >= NN) return;
    int start = row_ptr[n], end = row_ptr[n + 1];
    float4 adv = ((const float4*)ad)[n];
    int whead = lane >> 4;
    float4 acc = make_float4(0.f, 0.f, 0.f, 0.f);
    float d0 = 0.f, d1 = 0.f, d2 = 0.f, d3 = 0.f;
    for (int c0 = start; c0 < end; c0 += 64) {
        int m = min(64, end - c0);
        if (lane < m) {
            int s = csr_src[c0 + lane];
            ssrc[wv][lane] = s;
            float4 asv = ((const float4*)as)[s];
            float e0 = asv.x + adv.x; e0 = e0 > 0.f ? e0 : 0.2f * e0; float x0 = __expf(e0);
            float e1 = asv.y + adv.y; e1 = e1 > 0.f ? e1 : 0.2f * e1; float x1 = __expf(e1);
            float e2 = asv.z + adv.z; e2 = e2 > 0.f ? e2 : 0.2f * e2; float x2 = __expf(e2);
            float e3 = asv.w + adv.w; e3 = e3 > 0.f ? e3 : 0.2f * e3; float x3 = __expf(e3);
            *(float4*)&wch[wv][lane][0] = make_float4(x0, x1, x2, x3);
            d0 += x0; d1 += x1; d2 += x2; d3 += x3;
        }
        int j = 0;
        for (; j + 4 <= m; j += 4) {
            int   sj[4]; float wj[4]; ushort4 hv[4];
            #pragma unroll
            for (int u = 0; u < 4; u++) {
                sj[u] = ssrc[wv][j + u];
                wj[u] = wch[wv][j + u][whead];
            }
            #pragma unroll
            for (int u = 0; u < 4; u++)
                hv[u] = ((const ushort4*)h1b)[(size_t)sj[u] * 64 + lane];
            #pragma unroll
            for (int u = 0; u < 4; u++) {
                acc.x += bf2f(hv[u].x) * wj[u]; acc.y += bf2f(hv[u].y) * wj[u];
                acc.z += bf2f(hv[u].z) * wj[u]; acc.w += bf2f(hv[u].w) * wj[u];
            }
        }
        for (; j < m; j++) {
            int s = ssrc[wv][j];
            float w = wch[wv][j][whead];
            ushort4 hv = ((const ushort4*)h1b)[(size_t)s * 64 + lane];
            acc.x += bf2f(hv.x) * w; acc.y += bf2f(hv.y) * w;
            acc.z += bf2f(hv.z) * w; acc.w += bf2f(hv.w) * w;
        }
    }
    #pragma unroll
    for (int off = 32; off; off >>= 1) {
        d0 += __shfl_down(d0, off); d1 += __shfl_down(d1, off);
        d2 += __shfl_down(d2, off); d3 += __shfl_down(d3, off);
    }
    d0 = __shfl(d0, 0); d1 = __shfl(d1, 0);
    d2 = __shfl(d2, 0); d3 = __shfl(d3, 0);
    float den = whead == 0 ? d0 : whead == 1 ? d1 : whead == 2 ? d2 : d3;
    float inv = 1.f / (den + 1e-16f);
    float4 bv = ((const float4*)b1)[lane];
    float4 r;
    r.x = acc.x * inv + bv.x; r.y = acc.y * inv + bv.y;
    r.z = acc.z * inv + bv.z; r.w = acc.w * inv + bv.w;
    r.x = r.x > 0.f ? r.x : expm1f(r.x);
    r.y = r.y > 0.f ? r.y : expm1f(r.y);
    r.z = r.z > 0.f ? r.z : expm1f(r.z);
    r.w = r.w > 0.f ? r.w : expm1f(r.w);
    ushort4 hi4, lo4;
    hi4.x = f2bf(r.x); lo4.x = f2bf(r.x - bf2f(hi4.x));
    hi4.y = f2bf(r.y); lo4.y = f2bf(r.y - bf2f(hi4.y));
    hi4.z = f2bf(r.z); lo4.z = f2bf(r.z - bf2f(hi4.z));
    hi4.w = f2bf(r.w); lo4.w = f2bf(r.w - bf2f(hi4.w));
    ((ushort4*)h2hi)[(size_t)n * 64 + lane] = hi4;
    ((ushort4*)h2lo)[(size_t)n * 64 + lane] = lo4;
}

// ---------------- layer-2 aggregation: wave = node, unroll-4 gather ----------------
__global__ __launch_bounds__(256) void agg2_kernel(
        const unsigned short* __restrict__ g2b, const int* __restrict__ row_ptr,
        const int* __restrict__ csr_src, const float* __restrict__ as,
        const float* __restrict__ ad, const float* __restrict__ b2,
        float* __restrict__ out) {
    __shared__ int   ssrc[4][64];
    __shared__ float wts[4][64];
    int tid = threadIdx.x;
    int wv = tid >> 6, lane = tid & 63;
    int n = blockIdx.x * 4 + wv;
    if (n >= NN) return;
    int start = row_ptr[n], end = row_ptr[n + 1];
    float adv = ad[n];
    float acc = 0.f;
    float den = 0.f;
    for (int c0 = start; c0 < end; c0 += 64) {
        int m = min(64, end - c0);
        if (lane < m) {
            int s = csr_src[c0 + lane];
            ssrc[wv][lane] = s;
            float e = as[s] + adv;
            e = e > 0.f ? e : 0.2f * e;
            float x = __expf(e);
            wts[wv][lane] = x;
            den += x;
        }
        int j = 0;
        for (; j + 4 <= m; j += 4) {
            int sj[4]; float wj[4]; unsigned short gv[4];
            #pragma unroll
            for (int u = 0; u < 4; u++) {
                sj[u] = ssrc[wv][j + u];
                wj[u] = wts[wv][j + u];
            }
            #pragma unroll
            for (int u = 0; u < 4; u++)
                gv[u] = g2b[(size_t)sj[u] * 64 + lane];
            #pragma unroll
            for (int u = 0; u < 4; u++)
                acc += bf2f(gv[u]) * wj[u];
        }
        for (; j < m; j++) {
            int s = ssrc[wv][j];
            acc += bf2f(g2b[(size_t)s * 64 + lane]) * wts[wv][j];
        }
    }
    #pragma unroll
    for (int off = 32; off; off >>= 1) den += __shfl_down(den, off);
    den = __shfl(den, 0);
    float inv = 1.f / (den + 1e-16f);
    float r = acc * inv + b2[lane];
    out[(size_t)n * 64 + lane] = r > 0.f ? r : expm1f(r);
}

// ---------------- launch ----------------

extern "C" void kernel_launch(void* const* d_in, const int* in_sizes, int n_in,
                              void* d_out, int out_size, void* d_ws, size_t ws_size,
                              hipStream_t stream) {
    const float* x      = (const float*)d_in[0];
    const int*   ei     = (const int*)d_in[1];
    const float* W1     = (const float*)d_in[2];
    const float* a_src1 = (const float*)d_in[3];
    const float* a_dst1 = (const float*)d_in[4];
    const float* b1     = (const float*)d_in[5];
    const float* W2     = (const float*)d_in[6];
    const float* a_src2 = (const float*)d_in[7];
    const float* a_dst2 = (const float*)d_in[8];
    const float* b2     = (const float*)d_in[9];
    float* out = (float*)d_out;

    char* base = (char*)d_ws;
    size_t off = 0;
    auto alloc = [&](size_t bytes) -> void* {
        void* p = base + off;
        off = (off + bytes + 255) & ~(size_t)255;
        return p;
    };
    int*   deg     = (int*)alloc(NN * sizeof(int));
    int*   bsum    = (int*)alloc(SCAN_BLOCKS * sizeof(int));
    int*   boff    = (int*)alloc(SCAN_BLOCKS * sizeof(int));
    int*   row_ptr = (int*)alloc((NN + 1) * sizeof(int));
    int*   cursor  = (int*)alloc(NN * sizeof(int));
    int*   csr_src = (int*)alloc(EE * sizeof(int));
    unsigned short* W1Thi = (unsigned short*)alloc(256 * 128 * 2);
    unsigned short* W1Tlo = (unsigned short*)alloc(256 * 128 * 2);
    unsigned short* W2Thi = (unsigned short*)alloc(64 * 256 * 2);
    unsigned short* W2Tlo = (unsigned short*)alloc(64 * 256 * 2);
    unsigned short* h1b   = (unsigned short*)alloc((size_t)NN * 256 * 2);
    float* as1     = (float*)alloc((size_t)NN * 4 * sizeof(float));
    float* ad1     = (float*)alloc((size_t)NN * 4 * sizeof(float));
    unsigned short* h2hi  = (unsigned short*)alloc((size_t)NN * 256 * 2);
    unsigned short* h2lo  = (unsigned short*)alloc((size_t)NN * 256 * 2);
    unsigned short* g2b   = (unsigned short*)alloc((size_t)NN * 64 * 2);
    float* as2     = (float*)alloc((size_t)NN * sizeof(float));
    float* ad2     = (float*)alloc((size_t)NN * sizeof(float));

    hipMemsetAsync(deg, 0, NN * sizeof(int), stream);

    // degree histogram + W1/W2 transpose-splits in one launch
    prep_kernel<<<EBLOCKS + 128 + 64, 256, 0, stream>>>(ei, deg, W1, W1Thi, W1Tlo,
                                                        W2, W2Thi, W2Tlo);
    deg_partial_kernel<<<SCAN_BLOCKS, 256, 0, stream>>>(deg, bsum);
    scanb_kernel<<<1, 256, 0, stream>>>(bsum, boff, row_ptr);
    fill_kernel<<<SCAN_BLOCKS, 256, 0, stream>>>(deg, boff, row_ptr, cursor);
    scatter_kernel<<<EBLOCKS, 256, 0, stream>>>(ei, cursor, csr_src);

    // layer 1
    gemm1_mfma<<<(NN + 31) / 32, 256, 0, stream>>>(x, W1Thi, W1Tlo,
                                                   a_src1, a_dst1, h1b, as1, ad1);
    agg1_kernel<<<(NN + 3) / 4, 256, 0, stream>>>(h1b, row_ptr, csr_src, as1, ad1, b1,
                                                  h2hi, h2lo);

    // layer 2
    gemm2_mfma<<<(NN + 127) / 128, 256, 0, stream>>>(h2hi, h2lo, W2Thi, W2Tlo,
                                                     a_src2, a_dst2, g2b, as2, ad2);
    agg2_kernel<<<(NN + 3) / 4, 256, 0, stream>>>(g2b, row_ptr, csr_src, as2, ad2, b2, out);
}